// Round 12
// baseline (2886.128 us; speedup 1.0000x reference)
//
#include <hip/hip_runtime.h>
#include <hip/hip_bf16.h>
#include <cmath>

// Problem dims
#define Bb 128
#define Tt 512
#define Ii 512
#define Hh 2048
#define Oo 512
#define REC_GRID 256

typedef __bf16 bf16_t;
typedef __bf16 bf16x8 __attribute__((ext_vector_type(8)));
typedef __bf16 bf16x4 __attribute__((ext_vector_type(4)));
typedef float  f32x4_t __attribute__((ext_vector_type(4)));
typedef unsigned long long u64;
typedef unsigned u32;

static __device__ __forceinline__ bf16_t to_b(float v){ return (bf16_t)v; }
static __device__ __forceinline__ float  b2f(unsigned short u){ unsigned x = ((unsigned)u)<<16; return __builtin_bit_cast(float, x); }
static __device__ __forceinline__ unsigned short f2bbits(float v){ return __builtin_bit_cast(unsigned short, to_b(v)); }

// async global->LDS, 16B per lane: LDS dest = uniform base + lane*16, global
// source is PER-LANE (T21/m173) -- fragment-order landing via source scatter.
static __device__ __forceinline__ void gl_lds16(const void* g, void* l){
  __builtin_amdgcn_global_load_lds((const __attribute__((address_space(1))) void*)g,
                                   (__attribute__((address_space(3))) void*)l, 16, 0, 0);
}

#define REP8(M) M(0)M(1)M(2)M(3)M(4)M(5)M(6)M(7)

// ---------- small prep kernels ----------
__global__ __launch_bounds__(256) void k_f2b(bf16_t* __restrict__ dst, const float* __restrict__ src){
  size_t i = ((size_t)blockIdx.x*256 + threadIdx.x)*4;
  float4 v = *(const float4*)(src + i);
  bf16x4 o; o[0]=to_b(v.x); o[1]=to_b(v.y); o[2]=to_b(v.z); o[3]=to_b(v.w);
  *(bf16x4*)(dst + i) = o;
}

__global__ __launch_bounds__(256) void k_init_h0(const float* __restrict__ hi_w, const float* __restrict__ hi_b,
                                                 bf16_t* __restrict__ h0b){
  int i = blockIdx.x*256 + threadIdx.x;           // [0, H)
  bf16_t vb = to_b(hi_w[i] + hi_b[i]);
  for (int b=0;b<Bb;++b) h0b[(size_t)b*Hh + i] = vb;
}

__global__ __launch_bounds__(256) void k_convert_x(const float* __restrict__ x, bf16_t* __restrict__ x_tm){
  size_t idx = ((size_t)blockIdx.x*256 + threadIdx.x)*8;
  int    i0  = (int)(idx % Ii);
  size_t m   = idx / Ii;                          // m = t*B + b
  int    t   = (int)(m / Bb), b = (int)(m % Bb);
  const float* s = x + ((size_t)b*Tt + t)*Ii + i0;
  float4 v0 = *(const float4*)s, v1 = *(const float4*)(s+4);
  bf16x8 o;
  o[0]=to_b(v0.x); o[1]=to_b(v0.y); o[2]=to_b(v0.z); o[3]=to_b(v0.w);
  o[4]=to_b(v1.x); o[5]=to_b(v1.y); o[6]=to_b(v1.z); o[7]=to_b(v1.w);
  *(bf16x8*)(x_tm + idx) = o;
}

// ---------- GEMM building blocks (encoder / decoder) ----------
template<int ROWS, int KB>
static __device__ __forceinline__ void stage(const bf16_t* __restrict__ g, long ld, long row0, int k0,
                                             char* __restrict__ ldsT){
  constexpr int SLOTS = KB/8;
  constexpr int PT    = ROWS*SLOTS/256;
  #pragma unroll
  for (int j=0;j<PT;++j){
    int c    = threadIdx.x + 256*j;
    int row  = c / SLOTS, slot = c % SLOTS;
    uint4 v  = *(const uint4*)(g + (row0+row)*ld + k0 + slot*8);
    *(uint4*)(ldsT + row*(KB*2) + ((slot*16) ^ ((row&7)<<4))) = v;
  }
}

template<int KB>
static __device__ __forceinline__ bf16x8 frag(const char* __restrict__ ldsT, int row, int kk, int lane){
  int kbyte = kk*64 + ((lane>>4)<<4);
  return *(const bf16x8*)(ldsT + row*(KB*2) + (kbyte ^ ((row&7)<<4)));
}

template<int EPI>
__global__ __launch_bounds__(256) void gemm128(const bf16_t* __restrict__ A, long lda,
                                               const bf16_t* __restrict__ Bw, long ldb,
                                               const float* __restrict__ bias,
                                               void* __restrict__ Cout, long ldc, int K){
  constexpr int TM=128, TN=128, KB=64;
  __shared__ char lds[(TM+TN)*KB*2];
  char* ldsA = lds;
  char* ldsB = lds + TM*KB*2;
  long m0 = (long)blockIdx.x * TM;
  long n0 = (long)blockIdx.y * TN;
  int w = threadIdx.x >> 6, lane = threadIdx.x & 63;
  int wm = w >> 1, wn = w & 1;
  f32x4_t acc[4][4] = {};
  for (int k0=0;k0<K;k0+=KB){
    __syncthreads();
    stage<TM,KB>(A,  lda, m0, k0, ldsA);
    stage<TN,KB>(Bw, ldb, n0, k0, ldsB);
    __syncthreads();
    #pragma unroll
    for (int kk=0;kk<KB/32;++kk){
      bf16x8 af[4], bfv[4];
      #pragma unroll
      for (int f=0;f<4;++f){ int r = wm*64 + f*16 + (lane&15); af[f]  = frag<KB>(ldsA, r, kk, lane); }
      #pragma unroll
      for (int f=0;f<4;++f){ int r = wn*64 + f*16 + (lane&15); bfv[f] = frag<KB>(ldsB, r, kk, lane); }
      #pragma unroll
      for (int i=0;i<4;++i)
        #pragma unroll
        for (int j=0;j<4;++j)
          acc[i][j] = __builtin_amdgcn_mfma_f32_16x16x32_bf16(af[i], bfv[j], acc[i][j], 0,0,0);
    }
  }
  #pragma unroll
  for (int i=0;i<4;++i)
    #pragma unroll
    for (int j=0;j<4;++j)
      #pragma unroll
      for (int e=0;e<4;++e){
        long row = m0 + wm*64 + i*16 + ((lane>>4)<<2) + e;
        long col = n0 + wn*64 + j*16 + (lane&15);
        float v = acc[i][j][e] + bias[col];
        if (EPI==0) ((bf16_t*)Cout)[row*ldc + col] = to_b(v);
        else        ((float*) Cout)[row*ldc + col] = v;
      }
}

// ---------- persistent recurrence kernel (512 threads / 8 waves) ----------
// 8 groups x 32 blocks; g = bid&7 -> one group per XCD (L2-local h slice).
// Group g owns batches 16g..+15; block (g,n) owns H-cols 64n..+63.
// Wave w = K-eighth [w*256,+256): W slice (64 cols x 256 K) = 32 named bf16x8
// (128 VGPRs, 4 col-groups x 8 kk), loaded via two 128KB fragment-order LDS
// passes that ALIAS the steady-state buffers (R10's no-asm register pinning).
// PER STEP: ONE 64KB volley in FRAGMENT ORDER (per-lane-scattered global src,
// linear LDS dst -- R5-proven) -> all h/W LDS reads are uniform+lane*16,
// conflict-free; 32 MFMAs/wave; 32KB 8-way K-reduction; u32 cooperative
// agent-atomic enc/h exchange; per-(group,step) atomicAdd barrier (target 32).
__global__ __launch_bounds__(512, 1) void rec_persist(
    const bf16_t* __restrict__ h0b, const bf16_t* __restrict__ W,
    bf16_t* __restrict__ EH, float* __restrict__ hfinal,
    const float* __restrict__ rec_b, const float* __restrict__ hi_w, const float* __restrict__ hi_b,
    const float* __restrict__ dtp, const float* __restrict__ ap,
    unsigned* __restrict__ cnt)
{
  __shared__ char lds[131072];           // init: W pass buffer; steady: hbuf+red+xb
  char* hbuf = lds;                      // 64 KB volley (64 chunks x 1KB)
  char* red  = lds + 65536;              // 32 KB reduction
  u32*  xb   = (u32*)(lds + 65536 + 32768); // 2 KB exchange

  const int bid = blockIdx.x;
  const int g   = bid & 7;               // batch group == XCD
  const int n   = bid >> 3;              // H tile 0..31
  const int m0  = g * 16;
  const int n0  = n * 64;
  unsigned* gcnt = cnt + g*512;
  const int tid = threadIdx.x, w = tid >> 6, lane = tid & 63;
  const int l15 = lane & 15, w8 = w*8;

  // ---- one-time: W -> 32 named VGPR frags via 2 fragment-order LDS passes ----
  // frag (cg, kkl): lane reads W[n0+cg*16+(lane&15)][(w*8+kkl)*32+(lane>>4)*8..+8]
  #define WDCL(i) bf16x8 wa##i, wb##i, wc##i, wd##i;
  REP8(WDCL)
  #undef WDCL
  #pragma unroll 1
  for (int p = 0; p < 2; ++p){
    __syncthreads();
    for (int it = 0; it < 16; ++it){
      int cid = it*512 + tid;            // 8192 chunks of 16B = 128KB
      int lc  = cid & 63, kk = (cid >> 6) & 63, cgl = cid >> 12;
      uint4 v = *(const uint4*)(W + (size_t)(n0 + p*32 + cgl*16 + (lc&15))*Hh + kk*32 + ((lc>>4)<<3));
      *(uint4*)(lds + (size_t)cid*16) = v;
    }
    __syncthreads();
    if (p == 0){
      #define WRD0(i) \
        wa##i = *(const bf16x8*)(lds + (size_t)((      w8 + (i))*64 + lane)*16); \
        wb##i = *(const bf16x8*)(lds + (size_t)((4096/64*0 + 64 + w8 + (i))*64 + lane)*16);
      REP8(WRD0)
      #undef WRD0
    } else {
      #define WRD1(i) \
        wc##i = *(const bf16x8*)(lds + (size_t)((      w8 + (i))*64 + lane)*16); \
        wd##i = *(const bf16x8*)(lds + (size_t)((64 + w8 + (i))*64 + lane)*16);
      REP8(WRD1)
      #undef WRD1
    }
  }
  __syncthreads();                       // all W reads done; LDS reusable

  const float s  = 1.f/(1.f + __expf(-dtp[0]));
  const float av = ap[0];
  // output role: cg_o = w&3 (col group), eh = w>>2 (which e-pair of the frag)
  const int   cg_o = w & 3, eh = w >> 2;
  const int   batch = m0 + l15;                          // C col = lane&15 -> batch
  const int   hcol0 = n0 + cg_o*16 + ((lane>>4)<<2) + eh*2;  // 2 cols/thread
  const int   lslot = l15*32 + cg_o*8 + (lane>>4)*2 + eh;
  float rb[2], hm[2];
  #pragma unroll
  for (int e=0;e<2;++e){ rb[e] = rec_b[hcol0+e]; hm[e] = hi_w[hcol0+e] + hi_b[hcol0+e]; }

  // volley source (per-lane scatter, fragment order): chunk kk <- 
  // h[m0 + (lane&15)][kk*32 + (lane>>4)*8 ..+8]
  const size_t vsrc_off = (size_t)(m0 + l15)*Hh + ((lane>>4)<<3);
  // cooperative enc/h slot: thread tid -> batch tid>>5, col pair tid&31
  const int co_b = m0 + (tid >> 5);
  const int co_c = n0 + (tid & 31)*2;

  for (int t = 0; t < Tt; ++t){
    const bf16_t* Asrc = (t==0) ? h0b : (EH + (size_t)(t-1)*(Bb*Hh));
    bf16_t* EHt = EH + (size_t)t*(Bb*Hh);

    // enc for this thread's cooperative slot (uncached agent load; overlaps volley)
    u32 ecv = __hip_atomic_load((const u32*)(EHt + (size_t)co_b*Hh + co_c),
                                __ATOMIC_RELAXED, __HIP_MEMORY_SCOPE_AGENT);

    // ONE 64KB volley, fragment order: wave w stages chunks w*8..w*8+7
    {
      const bf16_t* src = Asrc + vsrc_off;
      #pragma unroll
      for (int i = 0; i < 8; ++i)
        gl_lds16(src + (w8 + i)*32, hbuf + (size_t)(w8 + i)*1024);
    }
    __syncthreads();                     // volley complete (vmcnt drained at barrier)

    // K-loop: 8 conflict-free h ds_reads, 32 MFMAs (4 col-groups x 8 kk)
    f32x4_t acc0 = {0.f,0.f,0.f,0.f}, acc1 = acc0, acc2 = acc0, acc3 = acc0;
    #define KS(i) { \
      bf16x8 hv = *(const bf16x8*)(hbuf + (size_t)(w8 + (i))*1024 + (size_t)lane*16); \
      acc0 = __builtin_amdgcn_mfma_f32_16x16x32_bf16(wa##i, hv, acc0, 0,0,0); \
      acc1 = __builtin_amdgcn_mfma_f32_16x16x32_bf16(wb##i, hv, acc1, 0,0,0); \
      acc2 = __builtin_amdgcn_mfma_f32_16x16x32_bf16(wc##i, hv, acc2, 0,0,0); \
      acc3 = __builtin_amdgcn_mfma_f32_16x16x32_bf16(wd##i, hv, acc3, 0,0,0); }
    REP8(KS)
    #undef KS

    // cross-wave K-reduction: slot (srcwave, cg); conflict-free (uniform+lane*16)
    *(f32x4_t*)(red + (size_t)((w*4 + 0)*64 + lane)*16) = acc0;
    *(f32x4_t*)(red + (size_t)((w*4 + 1)*64 + lane)*16) = acc1;
    *(f32x4_t*)(red + (size_t)((w*4 + 2)*64 + lane)*16) = acc2;
    *(f32x4_t*)(red + (size_t)((w*4 + 3)*64 + lane)*16) = acc3;
    xb[tid] = ecv;
    __syncthreads();
    f32x4_t fa = *(const f32x4_t*)(red + (size_t)((0*4 + cg_o)*64 + lane)*16);
    #pragma unroll
    for (int q=1;q<8;++q) fa = fa + *(const f32x4_t*)(red + (size_t)((q*4 + cg_o)*64 + lane)*16);

    // epilogue: 2 cols/thread, u32 exchange, cooperative agent store
    u32 ev = xb[lslot];
    u32 ov = 0;
    #pragma unroll
    for (int e=0;e<2;++e){
      float enc = b2f((unsigned short)(ev >> (16*e)));
      float pre = enc + av*(fa[eh*2+e] + rb[e]);
      float th  = 1.f - 2.f/(__expf(2.f*pre) + 1.f);   // tanh
      hm[e] = (1.f - s)*hm[e] + s*th;
      ov |= ((u32)f2bbits(hm[e])) << (16*e);
    }
    xb[lslot] = ov;                      // same thread reads then writes its own slot
    __syncthreads();
    u32 hv = xb[tid];
    __hip_atomic_store((u32*)(EHt + (size_t)co_b*Hh + co_c), hv,
                       __ATOMIC_RELAXED, __HIP_MEMORY_SCOPE_AGENT);
    __syncthreads();                     // drains store acks (vmcnt0 before s_barrier)

    // group barrier: one counter per (group, step), target 32 (R4-proven form)
    if (tid == 0){
      __hip_atomic_fetch_add(gcnt + t, 1u, __ATOMIC_RELAXED, __HIP_MEMORY_SCOPE_AGENT);
      while (__hip_atomic_load(gcnt + t, __ATOMIC_RELAXED, __HIP_MEMORY_SCOPE_AGENT) < 32u) {}
    }
    __syncthreads();
  }

  // final hidden (f32) -> out tail
  #pragma unroll
  for (int e=0;e<2;++e) hfinal[(size_t)batch*Hh + hcol0 + e] = hm[e];
}

// ---------- launch ----------
extern "C" void kernel_launch(void* const* d_in, const int* in_sizes, int n_in,
                              void* d_out, int out_size, void* d_ws, size_t ws_size,
                              hipStream_t stream){
  const float* x     = (const float*)d_in[0];
  const float* dt    = (const float*)d_in[1];
  const float* a     = (const float*)d_in[2];
  const float* enc_w = (const float*)d_in[3];
  const float* enc_b = (const float*)d_in[4];
  const float* rec_w = (const float*)d_in[5];
  const float* rec_b = (const float*)d_in[6];
  const float* dec_w = (const float*)d_in[7];
  const float* dec_b = (const float*)d_in[8];
  const float* hi_w  = (const float*)d_in[9];
  const float* hi_b  = (const float*)d_in[10];
  float* out = (float*)d_out;

  // workspace carve-out (~333 MB)
  char* ws = (char*)d_ws;
  size_t off = 0;
  auto carve = [&](size_t bytes)->char*{ char* p = ws + off; off += (bytes + 255) & ~(size_t)255; return p; };
  bf16_t* x_tm   = (bf16_t*)carve((size_t)Tt*Bb*Ii*2);   // 64 MB
  bf16_t* EH     = (bf16_t*)carve((size_t)Tt*Bb*Hh*2);   // 256 MB  enc -> h history
  bf16_t* h0b    = (bf16_t*)carve((size_t)Bb*Hh*2);
  bf16_t* enc_wb = (bf16_t*)carve((size_t)Hh*Ii*2);
  bf16_t* rec_wb = (bf16_t*)carve((size_t)Hh*Hh*2);
  bf16_t* dec_wb = (bf16_t*)carve((size_t)Oo*Hh*2);
  unsigned* cnt  = (unsigned*)carve(8*512*4);             // per-(group,step) counters
  if (off > ws_size) return;  // diagnostic: leaves output zeroed

  // reset barrier counters every call (ws is not re-poisoned between replays)
  hipMemsetAsync(cnt, 0, 8*512*4, stream);

  // weights -> bf16
  k_f2b<<<(Hh*Ii)/1024, 256, 0, stream>>>(enc_wb, enc_w);
  k_f2b<<<(Hh*Hh)/1024, 256, 0, stream>>>(rec_wb, rec_w);
  k_f2b<<<(Oo*Hh)/1024, 256, 0, stream>>>(dec_wb, dec_w);
  k_init_h0<<<Hh/256, 256, 0, stream>>>(hi_w, hi_b, h0b);
  k_convert_x<<<((size_t)Tt*Bb*Ii/8)/256, 256, 0, stream>>>(x, x_tm);

  // encoder: EH[t*B+b, h] = x_tm @ enc_w^T + enc_b   (M=65536, K=512, N=2048)
  gemm128<0><<<dim3((Tt*Bb)/128, Hh/128), 256, 0, stream>>>(x_tm, Ii, enc_wb, Ii, enc_b, EH, Hh, Ii);

  // recurrence: one persistent cooperative kernel, 512 steps, 512 threads/block
  {
    float* hfinal = out + (size_t)Tt*Bb*Oo;
    void* args[] = { (void*)&h0b, (void*)&rec_wb, (void*)&EH, (void*)&hfinal,
                     (void*)&rec_b, (void*)&hi_w, (void*)&hi_b, (void*)&dt, (void*)&a,
                     (void*)&cnt };
    hipLaunchCooperativeKernel((const void*)rec_persist, dim3(REC_GRID), dim3(512), args, 0, stream);
  }

  // decoder: out[t*B+b, o] = EH @ dec_w^T + dec_b   (M=65536, K=2048, N=512)
  gemm128<1><<<dim3((Tt*Bb)/128, Oo/128), 256, 0, stream>>>(EH, Hh, dec_wb, Hh, dec_b, out, Oo, Hh);
}

// Round 13
// 2637.609 us; speedup vs baseline: 1.0942x; 1.0942x over previous
//
#include <hip/hip_runtime.h>
#include <hip/hip_bf16.h>
#include <cmath>

// Problem dims
#define Bb 128
#define Tt 512
#define Ii 512
#define Hh 2048
#define Oo 512
#define REC_GRID 256

typedef __bf16 bf16_t;
typedef __bf16 bf16x8 __attribute__((ext_vector_type(8)));
typedef __bf16 bf16x4 __attribute__((ext_vector_type(4)));
typedef float  f32x4_t __attribute__((ext_vector_type(4)));
typedef unsigned u32;

static __device__ __forceinline__ bf16_t to_b(float v){ return (bf16_t)v; }
static __device__ __forceinline__ float  b2f(unsigned short u){ unsigned x = ((unsigned)u)<<16; return __builtin_bit_cast(float, x); }
static __device__ __forceinline__ unsigned short f2bbits(float v){ return __builtin_bit_cast(unsigned short, to_b(v)); }

// async global->LDS, 16B per lane: LDS dest = uniform base + lane*16, global
// source is PER-LANE (T21/m173) -- fragment-order landing via source scatter.
static __device__ __forceinline__ void gl_lds16(const void* g, void* l){
  __builtin_amdgcn_global_load_lds((const __attribute__((address_space(1))) void*)g,
                                   (__attribute__((address_space(3))) void*)l, 16, 0, 0);
}

#define REP8(M) M(0)M(1)M(2)M(3)M(4)M(5)M(6)M(7)

// ---------- small prep kernels ----------
__global__ __launch_bounds__(256) void k_f2b(bf16_t* __restrict__ dst, const float* __restrict__ src){
  size_t i = ((size_t)blockIdx.x*256 + threadIdx.x)*4;
  float4 v = *(const float4*)(src + i);
  bf16x4 o; o[0]=to_b(v.x); o[1]=to_b(v.y); o[2]=to_b(v.z); o[3]=to_b(v.w);
  *(bf16x4*)(dst + i) = o;
}

__global__ __launch_bounds__(256) void k_init_h0(const float* __restrict__ hi_w, const float* __restrict__ hi_b,
                                                 bf16_t* __restrict__ h0b){
  int i = blockIdx.x*256 + threadIdx.x;           // [0, H)
  bf16_t vb = to_b(hi_w[i] + hi_b[i]);
  for (int b=0;b<Bb;++b) h0b[(size_t)b*Hh + i] = vb;
}

__global__ __launch_bounds__(256) void k_convert_x(const float* __restrict__ x, bf16_t* __restrict__ x_tm){
  size_t idx = ((size_t)blockIdx.x*256 + threadIdx.x)*8;
  int    i0  = (int)(idx % Ii);
  size_t m   = idx / Ii;                          // m = t*B + b
  int    t   = (int)(m / Bb), b = (int)(m % Bb);
  const float* s = x + ((size_t)b*Tt + t)*Ii + i0;
  float4 v0 = *(const float4*)s, v1 = *(const float4*)(s+4);
  bf16x8 o;
  o[0]=to_b(v0.x); o[1]=to_b(v0.y); o[2]=to_b(v0.z); o[3]=to_b(v0.w);
  o[4]=to_b(v1.x); o[5]=to_b(v1.y); o[6]=to_b(v1.z); o[7]=to_b(v1.w);
  *(bf16x8*)(x_tm + idx) = o;
}

// ---------- GEMM building blocks (encoder / decoder) ----------
template<int ROWS, int KB>
static __device__ __forceinline__ void stage(const bf16_t* __restrict__ g, long ld, long row0, int k0,
                                             char* __restrict__ ldsT){
  constexpr int SLOTS = KB/8;
  constexpr int PT    = ROWS*SLOTS/256;
  #pragma unroll
  for (int j=0;j<PT;++j){
    int c    = threadIdx.x + 256*j;
    int row  = c / SLOTS, slot = c % SLOTS;
    uint4 v  = *(const uint4*)(g + (row0+row)*ld + k0 + slot*8);
    *(uint4*)(ldsT + row*(KB*2) + ((slot*16) ^ ((row&7)<<4))) = v;
  }
}

template<int KB>
static __device__ __forceinline__ bf16x8 frag(const char* __restrict__ ldsT, int row, int kk, int lane){
  int kbyte = kk*64 + ((lane>>4)<<4);
  return *(const bf16x8*)(ldsT + row*(KB*2) + (kbyte ^ ((row&7)<<4)));
}

template<int EPI>
__global__ __launch_bounds__(256) void gemm128(const bf16_t* __restrict__ A, long lda,
                                               const bf16_t* __restrict__ Bw, long ldb,
                                               const float* __restrict__ bias,
                                               void* __restrict__ Cout, long ldc, int K){
  constexpr int TM=128, TN=128, KB=64;
  __shared__ char lds[(TM+TN)*KB*2];
  char* ldsA = lds;
  char* ldsB = lds + TM*KB*2;
  long m0 = (long)blockIdx.x * TM;
  long n0 = (long)blockIdx.y * TN;
  int w = threadIdx.x >> 6, lane = threadIdx.x & 63;
  int wm = w >> 1, wn = w & 1;
  f32x4_t acc[4][4] = {};
  for (int k0=0;k0<K;k0+=KB){
    __syncthreads();
    stage<TM,KB>(A,  lda, m0, k0, ldsA);
    stage<TN,KB>(Bw, ldb, n0, k0, ldsB);
    __syncthreads();
    #pragma unroll
    for (int kk=0;kk<KB/32;++kk){
      bf16x8 af[4], bfv[4];
      #pragma unroll
      for (int f=0;f<4;++f){ int r = wm*64 + f*16 + (lane&15); af[f]  = frag<KB>(ldsA, r, kk, lane); }
      #pragma unroll
      for (int f=0;f<4;++f){ int r = wn*64 + f*16 + (lane&15); bfv[f] = frag<KB>(ldsB, r, kk, lane); }
      #pragma unroll
      for (int i=0;i<4;++i)
        #pragma unroll
        for (int j=0;j<4;++j)
          acc[i][j] = __builtin_amdgcn_mfma_f32_16x16x32_bf16(af[i], bfv[j], acc[i][j], 0,0,0);
    }
  }
  #pragma unroll
  for (int i=0;i<4;++i)
    #pragma unroll
    for (int j=0;j<4;++j)
      #pragma unroll
      for (int e=0;e<4;++e){
        long row = m0 + wm*64 + i*16 + ((lane>>4)<<2) + e;
        long col = n0 + wn*64 + j*16 + (lane&15);
        float v = acc[i][j][e] + bias[col];
        if (EPI==0) ((bf16_t*)Cout)[row*ldc + col] = to_b(v);
        else        ((float*) Cout)[row*ldc + col] = v;
      }
}

// ---------- persistent recurrence kernel (512 threads / 8 waves) ----------
// R12 structure (passed): 8 groups x 32 blocks, g=bid&7 (XCD-local h slice);
// group g owns batches 16g..+15; block (g,n) owns H-cols 64n..+63; wave w =
// K-eighth; W = 32 named VGPR frags via aliased fragment-order LDS passes;
// fragment-order 64KB volley (conflict-free reads); 32KB 8-way K-reduction;
// u32 cooperative agent exchange.
// NEW (R13): sync de-serialization. Per-block FLAG (64B stride, value t+1)
// replaces the 32-serialized-atomicAdd counter. Wave w depends only on its 4
// producer blocks (n = 4w..4w+3) -> wave-local poll with s_sleep backoff; the
// post-volley block barrier becomes a wave-local vmcnt(0) (chunks are
// wave-private). Block-wide syncs: 5 -> 3 per step.
__global__ __launch_bounds__(512, 1) void rec_persist(
    const bf16_t* __restrict__ h0b, const bf16_t* __restrict__ W,
    bf16_t* __restrict__ EH, float* __restrict__ hfinal,
    const float* __restrict__ rec_b, const float* __restrict__ hi_w, const float* __restrict__ hi_b,
    const float* __restrict__ dtp, const float* __restrict__ ap,
    unsigned* __restrict__ flags)
{
  __shared__ char lds[131072];           // init: W pass buffer; steady: hbuf+red+xb
  char* hbuf = lds;                      // 64 KB volley (64 chunks x 1KB)
  char* red  = lds + 65536;              // 32 KB reduction
  u32*  xb   = (u32*)(lds + 65536 + 32768); // 2 KB exchange

  const int bid = blockIdx.x;
  const int g   = bid & 7;               // batch group == XCD (locality heuristic)
  const int n   = bid >> 3;              // H tile 0..31
  const int m0  = g * 16;
  const int n0  = n * 64;
  unsigned* gflags = flags + g*32*16;    // 32 flags, 64B stride
  const int tid = threadIdx.x, w = tid >> 6, lane = tid & 63;
  const int l15 = lane & 15, w8 = w*8;

  // ---- one-time: W -> 32 named VGPR frags via 2 fragment-order LDS passes ----
  #define WDCL(i) bf16x8 wa##i, wb##i, wc##i, wd##i;
  REP8(WDCL)
  #undef WDCL
  #pragma unroll 1
  for (int p = 0; p < 2; ++p){
    __syncthreads();
    for (int it = 0; it < 16; ++it){
      int cid = it*512 + tid;            // 8192 chunks of 16B = 128KB
      int lc  = cid & 63, kk = (cid >> 6) & 63, cgl = cid >> 12;
      uint4 v = *(const uint4*)(W + (size_t)(n0 + p*32 + cgl*16 + (lc&15))*Hh + kk*32 + ((lc>>4)<<3));
      *(uint4*)(lds + (size_t)cid*16) = v;
    }
    __syncthreads();
    if (p == 0){
      #define WRD0(i) \
        wa##i = *(const bf16x8*)(lds + (size_t)((     w8 + (i))*64 + lane)*16); \
        wb##i = *(const bf16x8*)(lds + (size_t)((64 + w8 + (i))*64 + lane)*16);
      REP8(WRD0)
      #undef WRD0
    } else {
      #define WRD1(i) \
        wc##i = *(const bf16x8*)(lds + (size_t)((     w8 + (i))*64 + lane)*16); \
        wd##i = *(const bf16x8*)(lds + (size_t)((64 + w8 + (i))*64 + lane)*16);
      REP8(WRD1)
      #undef WRD1
    }
  }
  __syncthreads();                       // all W reads done; LDS reusable

  const float s  = 1.f/(1.f + __expf(-dtp[0]));
  const float av = ap[0];
  // output role: cg_o = w&3 (col group), eh = w>>2 (which e-pair of the frag)
  const int   cg_o = w & 3, eh = w >> 2;
  const int   batch = m0 + l15;                          // C col = lane&15 -> batch
  const int   hcol0 = n0 + cg_o*16 + ((lane>>4)<<2) + eh*2;  // 2 cols/thread
  const int   lslot = l15*32 + cg_o*8 + (lane>>4)*2 + eh;
  float rb[2], hm[2];
  #pragma unroll
  for (int e=0;e<2;++e){ rb[e] = rec_b[hcol0+e]; hm[e] = hi_w[hcol0+e] + hi_b[hcol0+e]; }

  // volley source (per-lane scatter, fragment order; R12-proven)
  const size_t vsrc_off = (size_t)(m0 + l15)*Hh + ((lane>>4)<<3);
  // cooperative enc/h slot (R12-proven)
  const int co_b = m0 + (tid >> 5);
  const int co_c = n0 + (tid & 31)*2;
  // this wave's 4 producer-block flags (cols w*256..+256 come from n=4w..4w+3)
  const unsigned* fp = gflags + (w*4 + (lane & 3))*16;

  for (int t = 0; t < Tt; ++t){
    const bf16_t* Asrc = (t==0) ? h0b : (EH + (size_t)(t-1)*(Bb*Hh));
    bf16_t* EHt = EH + (size_t)t*(Bb*Hh);

    // enc load first (same-block data, no producer hazard) -- hides under poll
    u32 ecv = __hip_atomic_load((const u32*)(EHt + (size_t)co_b*Hh + co_c),
                                __ATOMIC_RELAXED, __HIP_MEMORY_SCOPE_AGENT);

    // wave-local wait: only this wave's 4 producers must have finished step t-1
    if (t){
      unsigned tt = (unsigned)t;
      for (;;){
        unsigned v = __hip_atomic_load(fp, __ATOMIC_RELAXED, __HIP_MEMORY_SCOPE_AGENT);
        if (__all((int)(v >= tt))) break;
        __builtin_amdgcn_s_sleep(2);
      }
    }

    // ONE 64KB volley, fragment order: wave w stages (and later reads) ONLY
    // chunks w*8..w*8+7 -> wave-local vmcnt wait, no block barrier
    {
      const bf16_t* src = Asrc + vsrc_off;
      #pragma unroll
      for (int i = 0; i < 8; ++i)
        gl_lds16(src + (w8 + i)*32, hbuf + (size_t)(w8 + i)*1024);
    }
    asm volatile("s_waitcnt vmcnt(0)" ::: "memory");   // volley + ecv complete (this wave)

    // K-loop: 8 conflict-free h ds_reads, 32 MFMAs (4 col-groups x 8 kk)
    f32x4_t acc0 = {0.f,0.f,0.f,0.f}, acc1 = acc0, acc2 = acc0, acc3 = acc0;
    #define KS(i) { \
      bf16x8 hv = *(const bf16x8*)(hbuf + (size_t)(w8 + (i))*1024 + (size_t)lane*16); \
      acc0 = __builtin_amdgcn_mfma_f32_16x16x32_bf16(wa##i, hv, acc0, 0,0,0); \
      acc1 = __builtin_amdgcn_mfma_f32_16x16x32_bf16(wb##i, hv, acc1, 0,0,0); \
      acc2 = __builtin_amdgcn_mfma_f32_16x16x32_bf16(wc##i, hv, acc2, 0,0,0); \
      acc3 = __builtin_amdgcn_mfma_f32_16x16x32_bf16(wd##i, hv, acc3, 0,0,0); }
    REP8(KS)
    #undef KS

    // cross-wave K-reduction (red/xb free since last step's final barrier)
    *(f32x4_t*)(red + (size_t)((w*4 + 0)*64 + lane)*16) = acc0;
    *(f32x4_t*)(red + (size_t)((w*4 + 1)*64 + lane)*16) = acc1;
    *(f32x4_t*)(red + (size_t)((w*4 + 2)*64 + lane)*16) = acc2;
    *(f32x4_t*)(red + (size_t)((w*4 + 3)*64 + lane)*16) = acc3;
    xb[tid] = ecv;
    __syncthreads();                     // B: red/xb writes visible
    f32x4_t fa = *(const f32x4_t*)(red + (size_t)((0*4 + cg_o)*64 + lane)*16);
    #pragma unroll
    for (int q=1;q<8;++q) fa = fa + *(const f32x4_t*)(red + (size_t)((q*4 + cg_o)*64 + lane)*16);

    // epilogue: 2 cols/thread, u32 exchange, cooperative agent store
    u32 ev = xb[lslot];
    u32 ov = 0;
    #pragma unroll
    for (int e=0;e<2;++e){
      float enc = b2f((unsigned short)(ev >> (16*e)));
      float pre = enc + av*(fa[eh*2+e] + rb[e]);
      float th  = 1.f - 2.f/(__expf(2.f*pre) + 1.f);   // tanh
      hm[e] = (1.f - s)*hm[e] + s*th;
      ov |= ((u32)f2bbits(hm[e])) << (16*e);
    }
    xb[lslot] = ov;                      // same thread reads then writes its own slot
    __syncthreads();                     // C: h-packed exchange visible
    u32 hv = xb[tid];
    __hip_atomic_store((u32*)(EHt + (size_t)co_b*Hh + co_c), hv,
                       __ATOMIC_RELAXED, __HIP_MEMORY_SCOPE_AGENT);
    __syncthreads();                     // D: all waves' stores drained (vmcnt0/wave)
    if (tid == 0)
      __hip_atomic_store(gflags + n*16, (unsigned)(t+1),
                         __ATOMIC_RELAXED, __HIP_MEMORY_SCOPE_AGENT);
  }

  // final hidden (f32) -> out tail
  #pragma unroll
  for (int e=0;e<2;++e) hfinal[(size_t)batch*Hh + hcol0 + e] = hm[e];
}

// ---------- launch ----------
extern "C" void kernel_launch(void* const* d_in, const int* in_sizes, int n_in,
                              void* d_out, int out_size, void* d_ws, size_t ws_size,
                              hipStream_t stream){
  const float* x     = (const float*)d_in[0];
  const float* dt    = (const float*)d_in[1];
  const float* a     = (const float*)d_in[2];
  const float* enc_w = (const float*)d_in[3];
  const float* enc_b = (const float*)d_in[4];
  const float* rec_w = (const float*)d_in[5];
  const float* rec_b = (const float*)d_in[6];
  const float* dec_w = (const float*)d_in[7];
  const float* dec_b = (const float*)d_in[8];
  const float* hi_w  = (const float*)d_in[9];
  const float* hi_b  = (const float*)d_in[10];
  float* out = (float*)d_out;

  // workspace carve-out (~333 MB)
  char* ws = (char*)d_ws;
  size_t off = 0;
  auto carve = [&](size_t bytes)->char*{ char* p = ws + off; off += (bytes + 255) & ~(size_t)255; return p; };
  bf16_t* x_tm   = (bf16_t*)carve((size_t)Tt*Bb*Ii*2);   // 64 MB
  bf16_t* EH     = (bf16_t*)carve((size_t)Tt*Bb*Hh*2);   // 256 MB  enc -> h history
  bf16_t* h0b    = (bf16_t*)carve((size_t)Bb*Hh*2);
  bf16_t* enc_wb = (bf16_t*)carve((size_t)Hh*Ii*2);
  bf16_t* rec_wb = (bf16_t*)carve((size_t)Hh*Hh*2);
  bf16_t* dec_wb = (bf16_t*)carve((size_t)Oo*Hh*2);
  unsigned* flags = (unsigned*)carve(8*32*16*4);          // per-block flags, 64B stride
  if (off > ws_size) return;  // diagnostic: leaves output zeroed

  // reset flags every call (ws is not re-poisoned between replays)
  hipMemsetAsync(flags, 0, 8*32*16*4, stream);

  // weights -> bf16
  k_f2b<<<(Hh*Ii)/1024, 256, 0, stream>>>(enc_wb, enc_w);
  k_f2b<<<(Hh*Hh)/1024, 256, 0, stream>>>(rec_wb, rec_w);
  k_f2b<<<(Oo*Hh)/1024, 256, 0, stream>>>(dec_wb, dec_w);
  k_init_h0<<<Hh/256, 256, 0, stream>>>(hi_w, hi_b, h0b);
  k_convert_x<<<((size_t)Tt*Bb*Ii/8)/256, 256, 0, stream>>>(x, x_tm);

  // encoder: EH[t*B+b, h] = x_tm @ enc_w^T + enc_b   (M=65536, K=512, N=2048)
  gemm128<0><<<dim3((Tt*Bb)/128, Hh/128), 256, 0, stream>>>(x_tm, Ii, enc_wb, Ii, enc_b, EH, Hh, Ii);

  // recurrence: one persistent cooperative kernel, 512 steps, 512 threads/block
  {
    float* hfinal = out + (size_t)Tt*Bb*Oo;
    void* args[] = { (void*)&h0b, (void*)&rec_wb, (void*)&EH, (void*)&hfinal,
                     (void*)&rec_b, (void*)&hi_w, (void*)&hi_b, (void*)&dt, (void*)&a,
                     (void*)&flags };
    hipLaunchCooperativeKernel((const void*)rec_persist, dim3(REC_GRID), dim3(512), args, 0, stream);
  }

  // decoder: out[t*B+b, o] = EH @ dec_w^T + dec_b   (M=65536, K=2048, N=512)
  gemm128<1><<<dim3((Tt*Bb)/128, Oo/128), 256, 0, stream>>>(EH, Hh, dec_wb, Hh, dec_b, out, Oo, Hh);
}

// Round 14
// 2412.805 us; speedup vs baseline: 1.1962x; 1.0932x over previous
//
#include <hip/hip_runtime.h>
#include <hip/hip_bf16.h>
#include <cmath>

// Problem dims
#define Bb 128
#define Tt 512
#define Ii 512
#define Hh 2048
#define Oo 512
#define REC_GRID 256

typedef __bf16 bf16_t;
typedef __bf16 bf16x8 __attribute__((ext_vector_type(8)));
typedef __bf16 bf16x4 __attribute__((ext_vector_type(4)));
typedef float  f32x4_t __attribute__((ext_vector_type(4)));
typedef unsigned u32;

static __device__ __forceinline__ bf16_t to_b(float v){ return (bf16_t)v; }
static __device__ __forceinline__ float  b2f(unsigned short u){ unsigned x = ((unsigned)u)<<16; return __builtin_bit_cast(float, x); }
static __device__ __forceinline__ unsigned short f2bbits(float v){ return __builtin_bit_cast(unsigned short, to_b(v)); }

// async global->LDS, 16B per lane: LDS dest = uniform base + lane*16, global
// source is PER-LANE (T21/m173) -- fragment-order landing via source scatter.
static __device__ __forceinline__ void gl_lds16(const void* g, void* l){
  __builtin_amdgcn_global_load_lds((const __attribute__((address_space(1))) void*)g,
                                   (__attribute__((address_space(3))) void*)l, 16, 0, 0);
}

#define REP4(M) M(0)M(1)M(2)M(3)

// ---------- small prep kernels ----------
__global__ __launch_bounds__(256) void k_f2b(bf16_t* __restrict__ dst, const float* __restrict__ src){
  size_t i = ((size_t)blockIdx.x*256 + threadIdx.x)*4;
  float4 v = *(const float4*)(src + i);
  bf16x4 o; o[0]=to_b(v.x); o[1]=to_b(v.y); o[2]=to_b(v.z); o[3]=to_b(v.w);
  *(bf16x4*)(dst + i) = o;
}

__global__ __launch_bounds__(256) void k_init_h0(const float* __restrict__ hi_w, const float* __restrict__ hi_b,
                                                 bf16_t* __restrict__ h0b){
  int i = blockIdx.x*256 + threadIdx.x;           // [0, H)
  bf16_t vb = to_b(hi_w[i] + hi_b[i]);
  for (int b=0;b<Bb;++b) h0b[(size_t)b*Hh + i] = vb;
}

__global__ __launch_bounds__(256) void k_convert_x(const float* __restrict__ x, bf16_t* __restrict__ x_tm){
  size_t idx = ((size_t)blockIdx.x*256 + threadIdx.x)*8;
  int    i0  = (int)(idx % Ii);
  size_t m   = idx / Ii;                          // m = t*B + b
  int    t   = (int)(m / Bb), b = (int)(m % Bb);
  const float* s = x + ((size_t)b*Tt + t)*Ii + i0;
  float4 v0 = *(const float4*)s, v1 = *(const float4*)(s+4);
  bf16x8 o;
  o[0]=to_b(v0.x); o[1]=to_b(v0.y); o[2]=to_b(v0.z); o[3]=to_b(v0.w);
  o[4]=to_b(v1.x); o[5]=to_b(v1.y); o[6]=to_b(v1.z); o[7]=to_b(v1.w);
  *(bf16x8*)(x_tm + idx) = o;
}

// ---------- GEMM building blocks (encoder / decoder) ----------
template<int ROWS, int KB>
static __device__ __forceinline__ void stage(const bf16_t* __restrict__ g, long ld, long row0, int k0,
                                             char* __restrict__ ldsT){
  constexpr int SLOTS = KB/8;
  constexpr int PT    = ROWS*SLOTS/256;
  #pragma unroll
  for (int j=0;j<PT;++j){
    int c    = threadIdx.x + 256*j;
    int row  = c / SLOTS, slot = c % SLOTS;
    uint4 v  = *(const uint4*)(g + (row0+row)*ld + k0 + slot*8);
    *(uint4*)(ldsT + row*(KB*2) + ((slot*16) ^ ((row&7)<<4))) = v;
  }
}

template<int KB>
static __device__ __forceinline__ bf16x8 frag(const char* __restrict__ ldsT, int row, int kk, int lane){
  int kbyte = kk*64 + ((lane>>4)<<4);
  return *(const bf16x8*)(ldsT + row*(KB*2) + (kbyte ^ ((row&7)<<4)));
}

template<int EPI>
__global__ __launch_bounds__(256) void gemm128(const bf16_t* __restrict__ A, long lda,
                                               const bf16_t* __restrict__ Bw, long ldb,
                                               const float* __restrict__ bias,
                                               void* __restrict__ Cout, long ldc, int K){
  constexpr int TM=128, TN=128, KB=64;
  __shared__ char lds[(TM+TN)*KB*2];
  char* ldsA = lds;
  char* ldsB = lds + TM*KB*2;
  long m0 = (long)blockIdx.x * TM;
  long n0 = (long)blockIdx.y * TN;
  int w = threadIdx.x >> 6, lane = threadIdx.x & 63;
  int wm = w >> 1, wn = w & 1;
  f32x4_t acc[4][4] = {};
  for (int k0=0;k0<K;k0+=KB){
    __syncthreads();
    stage<TM,KB>(A,  lda, m0, k0, ldsA);
    stage<TN,KB>(Bw, ldb, n0, k0, ldsB);
    __syncthreads();
    #pragma unroll
    for (int kk=0;kk<KB/32;++kk){
      bf16x8 af[4], bfv[4];
      #pragma unroll
      for (int f=0;f<4;++f){ int r = wm*64 + f*16 + (lane&15); af[f]  = frag<KB>(ldsA, r, kk, lane); }
      #pragma unroll
      for (int f=0;f<4;++f){ int r = wn*64 + f*16 + (lane&15); bfv[f] = frag<KB>(ldsB, r, kk, lane); }
      #pragma unroll
      for (int i=0;i<4;++i)
        #pragma unroll
        for (int j=0;j<4;++j)
          acc[i][j] = __builtin_amdgcn_mfma_f32_16x16x32_bf16(af[i], bfv[j], acc[i][j], 0,0,0);
    }
  }
  #pragma unroll
  for (int i=0;i<4;++i)
    #pragma unroll
    for (int j=0;j<4;++j)
      #pragma unroll
      for (int e=0;e<4;++e){
        long row = m0 + wm*64 + i*16 + ((lane>>4)<<2) + e;
        long col = n0 + wn*64 + j*16 + (lane&15);
        float v = acc[i][j][e] + bias[col];
        if (EPI==0) ((bf16_t*)Cout)[row*ldc + col] = to_b(v);
        else        ((float*) Cout)[row*ldc + col] = v;
      }
}

// ---------- persistent recurrence kernel (1024 threads / 16 waves) ----------
// 8 groups x 32 blocks (g=bid&7, XCD-local); group g owns batches 16g..+15;
// block (g,n) owns H-cols 64n..+63. Wave w = K-SIXTEENTH [w*128,+128):
// W slice = 4 col-groups x 4 kk = 16 named bf16x8 (64 VGPRs -- fits the
// 128-reg budget at 4 waves/SIMD, no remat pressure), loaded via the proven
// 2-pass fragment-order LDS alias. Volley chunks are wave-private (4 gl_lds,
// fragment-order source scatter, wave-local vmcnt -- R13-proven, no barrier).
// Poll: 2 producer blocks per wave. Reduction: scalar PLANES (lane-stride-4B,
// conflict-free both sides). Output: 1 element/thread (cg_o=w&3, e=w>>2).
// Epilogue: 65-padded f32 LDS exchange + cooperative u32 agent load/store.
__global__ __launch_bounds__(1024, 1) void rec_persist(
    const bf16_t* __restrict__ h0b, const bf16_t* __restrict__ W,
    bf16_t* __restrict__ EH, float* __restrict__ hfinal,
    const float* __restrict__ rec_b, const float* __restrict__ hi_w, const float* __restrict__ hi_b,
    const float* __restrict__ dtp, const float* __restrict__ ap,
    unsigned* __restrict__ flags)
{
  __shared__ char lds[65536 + 65536 + 4352];   // hbuf + redf + xbf (init aliases first 128K)
  char*  hbuf = lds;                           // 64 KB volley (64 chunks x 1KB)
  float* redf = (float*)(lds + 65536);         // 64 KB: 256 planes x 64 lanes
  float* xbf  = (float*)(lds + 131072);        // 16 x 65 padded exchange

  const int bid = blockIdx.x;
  const int g   = bid & 7;               // batch group == XCD (locality heuristic)
  const int n   = bid >> 3;              // H tile 0..31
  const int m0  = g * 16;
  const int n0  = n * 64;
  unsigned* gflags = flags + g*32*16;    // 32 flags, 64B stride
  const int tid = threadIdx.x, w = tid >> 6, lane = tid & 63;
  const int l15 = lane & 15, w4 = w*4;

  // ---- one-time: W -> 16 named VGPR frags via 2 fragment-order LDS passes ----
  #define WDCL(i) bf16x8 wa##i, wb##i, wc##i, wd##i;
  REP4(WDCL)
  #undef WDCL
  #pragma unroll 1
  for (int p = 0; p < 2; ++p){
    __syncthreads();
    for (int it = 0; it < 8; ++it){
      int cid = it*1024 + tid;           // 8192 chunks of 16B = 128KB
      int lc  = cid & 63, kk = (cid >> 6) & 63, cgl = cid >> 12;
      uint4 v = *(const uint4*)(W + (size_t)(n0 + p*32 + cgl*16 + (lc&15))*Hh + kk*32 + ((lc>>4)<<3));
      *(uint4*)(lds + (size_t)cid*16) = v;
    }
    __syncthreads();
    if (p == 0){
      #define WRD(i) \
        wa##i = *(const bf16x8*)(lds + (size_t)((     w4 + (i))*64 + lane)*16); \
        wb##i = *(const bf16x8*)(lds + (size_t)((64 + w4 + (i))*64 + lane)*16);
      REP4(WRD)
      #undef WRD
    } else {
      #define WRD(i) \
        wc##i = *(const bf16x8*)(lds + (size_t)((     w4 + (i))*64 + lane)*16); \
        wd##i = *(const bf16x8*)(lds + (size_t)((64 + w4 + (i))*64 + lane)*16);
      REP4(WRD)
      #undef WRD
    }
  }
  __syncthreads();                       // all W reads done; LDS reusable

  const float s  = 1.f/(1.f + __expf(-dtp[0]));
  const float av = ap[0];
  // output role: 1 element per thread
  const int   cg_o = w & 3, eo = w >> 2;
  const int   batch = m0 + l15;
  const int   col_l = cg_o*16 + ((lane >> 4) << 2) + eo;
  const int   hcol  = n0 + col_l;
  const int   pos   = l15*65 + col_l;    // padded xbf slot
  const float rbv = rec_b[hcol];
  float hm = hi_w[hcol] + hi_b[hcol];

  // volley source (per-lane scatter, fragment order; R12-proven)
  const size_t vsrc_off = (size_t)(m0 + l15)*Hh + ((lane>>4)<<3);
  // cooperative enc/h slot (tid<512): batch tid>>5, col pair tid&31
  const int co_b = m0 + (tid >> 5);
  const int co_c = n0 + (tid & 31)*2;
  // this wave's 2 producer-block flags (cols w*128..+128 come from n'=2w,2w+1)
  const unsigned* fp = gflags + (w*2 + (lane & 1))*16;

  for (int t = 0; t < Tt; ++t){
    const bf16_t* Asrc = (t==0) ? h0b : (EH + (size_t)(t-1)*(Bb*Hh));
    bf16_t* EHt = EH + (size_t)t*(Bb*Hh);

    // enc load first (same-block data, no producer hazard) -- hides under poll
    u32 ecv = 0;
    if (tid < 512)
      ecv = __hip_atomic_load((const u32*)(EHt + (size_t)co_b*Hh + co_c),
                              __ATOMIC_RELAXED, __HIP_MEMORY_SCOPE_AGENT);

    // wave-local wait: only this wave's 2 producers must have finished t-1
    if (t){
      unsigned tt = (unsigned)t;
      for (;;){
        unsigned v = __hip_atomic_load(fp, __ATOMIC_RELAXED, __HIP_MEMORY_SCOPE_AGENT);
        if (__all((int)(v >= tt))) break;
        __builtin_amdgcn_s_sleep(2);
      }
    }

    // wave-private volley: stage + read only chunks w*4..w*4+3
    {
      const bf16_t* src = Asrc + vsrc_off;
      #pragma unroll
      for (int i = 0; i < 4; ++i)
        gl_lds16(src + (w4 + i)*32, hbuf + (size_t)(w4 + i)*1024);
    }
    asm volatile("s_waitcnt vmcnt(0)" ::: "memory");   // volley + ecv complete (this wave)

    // K-loop: 4 conflict-free h ds_reads, 16 MFMAs (4 col-groups x 4 kk)
    f32x4_t acc0 = {0.f,0.f,0.f,0.f}, acc1 = acc0, acc2 = acc0, acc3 = acc0;
    #define KS(i) { \
      bf16x8 hv = *(const bf16x8*)(hbuf + (size_t)(w4 + (i))*1024 + (size_t)lane*16); \
      acc0 = __builtin_amdgcn_mfma_f32_16x16x32_bf16(wa##i, hv, acc0, 0,0,0); \
      acc1 = __builtin_amdgcn_mfma_f32_16x16x32_bf16(wb##i, hv, acc1, 0,0,0); \
      acc2 = __builtin_amdgcn_mfma_f32_16x16x32_bf16(wc##i, hv, acc2, 0,0,0); \
      acc3 = __builtin_amdgcn_mfma_f32_16x16x32_bf16(wd##i, hv, acc3, 0,0,0); }
    REP4(KS)
    #undef KS

    // K-reduction via scalar planes: write lane-stride-4B (conflict-free)
    #pragma unroll
    for (int e=0;e<4;++e){
      redf[(w*16 +  0 + e)*64 + lane] = acc0[e];
      redf[(w*16 +  4 + e)*64 + lane] = acc1[e];
      redf[(w*16 +  8 + e)*64 + lane] = acc2[e];
      redf[(w*16 + 12 + e)*64 + lane] = acc3[e];
    }
    if (tid < 512){
      xbf[(tid>>5)*65 + (tid&31)*2    ] = b2f((unsigned short)(ecv & 0xffffu));
      xbf[(tid>>5)*65 + (tid&31)*2 + 1] = b2f((unsigned short)(ecv >> 16));
    }
    __syncthreads();                     // B: red planes + enc exchange visible

    float fa = 0.f;
    #pragma unroll
    for (int q=0;q<16;++q) fa += redf[(q*16 + cg_o*4 + eo)*64 + lane];

    // gated tanh update (1 element/thread); same-thread read-then-write on xbf[pos]
    {
      float enc = xbf[pos];
      float pre = enc + av*(fa + rbv);
      float th  = 1.f - 2.f/(__expf(2.f*pre) + 1.f);   // tanh
      hm = (1.f - s)*hm + s*th;
      xbf[pos] = hm;
    }
    __syncthreads();                     // C: h values in exchange

    if (tid < 512){
      float h0f = xbf[(tid>>5)*65 + (tid&31)*2];
      float h1f = xbf[(tid>>5)*65 + (tid&31)*2 + 1];
      u32 ov = (u32)f2bbits(h0f) | ((u32)f2bbits(h1f) << 16);
      __hip_atomic_store((u32*)(EHt + (size_t)co_b*Hh + co_c), ov,
                         __ATOMIC_RELAXED, __HIP_MEMORY_SCOPE_AGENT);
    }
    __syncthreads();                     // D: all waves' stores drained (vmcnt0/wave)
    if (tid == 0)
      __hip_atomic_store(gflags + n*16, (unsigned)(t+1),
                         __ATOMIC_RELAXED, __HIP_MEMORY_SCOPE_AGENT);
  }

  // final hidden (f32) -> out tail
  hfinal[(size_t)batch*Hh + hcol] = hm;
}

// ---------- launch ----------
extern "C" void kernel_launch(void* const* d_in, const int* in_sizes, int n_in,
                              void* d_out, int out_size, void* d_ws, size_t ws_size,
                              hipStream_t stream){
  const float* x     = (const float*)d_in[0];
  const float* dt    = (const float*)d_in[1];
  const float* a     = (const float*)d_in[2];
  const float* enc_w = (const float*)d_in[3];
  const float* enc_b = (const float*)d_in[4];
  const float* rec_w = (const float*)d_in[5];
  const float* rec_b = (const float*)d_in[6];
  const float* dec_w = (const float*)d_in[7];
  const float* dec_b = (const float*)d_in[8];
  const float* hi_w  = (const float*)d_in[9];
  const float* hi_b  = (const float*)d_in[10];
  float* out = (float*)d_out;

  // workspace carve-out (~333 MB)
  char* ws = (char*)d_ws;
  size_t off = 0;
  auto carve = [&](size_t bytes)->char*{ char* p = ws + off; off += (bytes + 255) & ~(size_t)255; return p; };
  bf16_t* x_tm   = (bf16_t*)carve((size_t)Tt*Bb*Ii*2);   // 64 MB
  bf16_t* EH     = (bf16_t*)carve((size_t)Tt*Bb*Hh*2);   // 256 MB  enc -> h history
  bf16_t* h0b    = (bf16_t*)carve((size_t)Bb*Hh*2);
  bf16_t* enc_wb = (bf16_t*)carve((size_t)Hh*Ii*2);
  bf16_t* rec_wb = (bf16_t*)carve((size_t)Hh*Hh*2);
  bf16_t* dec_wb = (bf16_t*)carve((size_t)Oo*Hh*2);
  unsigned* flags = (unsigned*)carve(8*32*16*4);          // per-block flags, 64B stride
  if (off > ws_size) return;  // diagnostic: leaves output zeroed

  // reset flags every call (ws is not re-poisoned between replays)
  hipMemsetAsync(flags, 0, 8*32*16*4, stream);

  // weights -> bf16
  k_f2b<<<(Hh*Ii)/1024, 256, 0, stream>>>(enc_wb, enc_w);
  k_f2b<<<(Hh*Hh)/1024, 256, 0, stream>>>(rec_wb, rec_w);
  k_f2b<<<(Oo*Hh)/1024, 256, 0, stream>>>(dec_wb, dec_w);
  k_init_h0<<<Hh/256, 256, 0, stream>>>(hi_w, hi_b, h0b);
  k_convert_x<<<((size_t)Tt*Bb*Ii/8)/256, 256, 0, stream>>>(x, x_tm);

  // encoder: EH[t*B+b, h] = x_tm @ enc_w^T + enc_b   (M=65536, K=512, N=2048)
  gemm128<0><<<dim3((Tt*Bb)/128, Hh/128), 256, 0, stream>>>(x_tm, Ii, enc_wb, Ii, enc_b, EH, Hh, Ii);

  // recurrence: one persistent cooperative kernel, 512 steps, 1024 threads/block
  {
    float* hfinal = out + (size_t)Tt*Bb*Oo;
    void* args[] = { (void*)&h0b, (void*)&rec_wb, (void*)&EH, (void*)&hfinal,
                     (void*)&rec_b, (void*)&hi_w, (void*)&hi_b, (void*)&dt, (void*)&a,
                     (void*)&flags };
    hipLaunchCooperativeKernel((const void*)rec_persist, dim3(REC_GRID), dim3(1024), args, 0, stream);
  }

  // decoder: out[t*B+b, o] = EH @ dec_w^T + dec_b   (M=65536, K=2048, N=512)
  gemm128<1><<<dim3((Tt*Bb)/128, Oo/128), 256, 0, stream>>>(EH, Hh, dec_wb, Hh, dec_b, out, Oo, Hh);
}